// Round 17
// baseline (23.016 us; speedup 1.0000x reference)
//
#include <hip/hip_runtime.h>

// Chamfer distance via MFMA: x,y (32,2048,3) f32 -> scalar f32.
// d(q,r) = |r|^2 - 2 q.r + |q|^2 as a K=16 bf16 dot (hi/lo split, ~1e-4 err):
//   ref  row A[16] = [xh,xl,xh,xl, yh,yl,yh,yl, zh,zl,zh,zl, nh,nl, 1, 1 ]
//   query col B[16] = [-2qxh,-2qxh,-2qxl,-2qxl, ..y,z.., 1,1, qnh,qnl]
// One v_mfma_f32_32x32x16_bf16 -> 32 refs x 32 queries; refs as A rows makes
// the per-query min within-lane.
//
// Round-17: R12 main body (tied-fastest) + fixed-cost cuts only:
//   * staging: 4 CONSECUTIVE points per thread via 3 x global_load_dwordx4
//     (48 contiguous bytes/lane; was 12 strided scalar loads)
//   * main loop fully unrolled (32): all ds_read offsets immediate
//   * K2 eliminated: hipMemsetAsync(d_out,0,4) + one pre-scaled
//     atomicAdd(out, blocksum/PTS) per block (no fences, no last-block logic;
//     fp reorder wobble ~1e-7 << 2.2e-3 threshold)
// LDS panel: conflict-free [tile][k-half][slot32] (round 10).

#define B_  32
#define N_  2048
#define PTS (B_ * N_)
#define ONEB 0x3F80u

typedef short  bf16x8 __attribute__((ext_vector_type(8)));
typedef float  f32x16 __attribute__((ext_vector_type(16)));

__device__ __forceinline__ unsigned short f2b(float f) {
    unsigned u = __float_as_uint(f);
    return (unsigned short)((u + 0x7FFFu + ((u >> 16) & 1u)) >> 16);  // RNE
}
__device__ __forceinline__ float b2f(unsigned short h) {
    return __uint_as_float(((unsigned)h) << 16);
}
#define PK(a, b) (((unsigned)(a)) | (((unsigned)(b)) << 16))

// 16 -> 1 min, min3-shaped (fuses to v_min3_f32): 8 ops.
__device__ __forceinline__ float min16(const f32x16 d) {
    const float a = fminf(fminf(d[0],  d[1]),  d[2]);
    const float b = fminf(fminf(d[3],  d[4]),  d[5]);
    const float c = fminf(fminf(d[6],  d[7]),  d[8]);
    const float e = fminf(fminf(d[9],  d[10]), d[11]);
    const float f = fminf(fminf(d[12], d[13]), d[14]);
    const float g = fminf(fminf(a, b), c);
    const float i = fminf(fminf(e, f), d[15]);
    return fminf(g, i);
}

__global__ __launch_bounds__(512, 4) void chamfer_mfma_kernel(
    const float* __restrict__ x, const float* __restrict__ y,
    float* __restrict__ out)
{
    __shared__ unsigned sB[N_ * 8];   // 64 KB, [tile][half][slot32] layout
    __shared__ float pm[2][4][64];    // 2 KB: [tile-half][stripe-pair][query]
    __shared__ float sred[4];

    const int bid  = blockIdx.x;      // 512
    const int dir  = bid >> 8;
    const int b    = (bid >> 3) & 31;
    const int qg   = bid & 7;         // 8 groups of 256 queries
    const int tid  = threadIdx.x;
    const int lane = tid & 63;
    const int wv   = tid >> 6;        // 0..7
    const int qs2  = wv & 3;          // stripe pair (64 queries)
    const int half = wv >> 2;         // which 32 ref tiles
    const int h    = lane >> 5;       // k-half
    const int ln31 = lane & 31;

    const float* q = dir ? y : x;
    const float* r = dir ? x : y;
    const float* rb = r + (size_t)b * N_ * 3;
    const float* qb = q + ((size_t)b * N_ + qg * 256 + qs2 * 64) * 3;

    // ---- stage ref panel: 4 CONSECUTIVE points per thread, float4 loads ----
    {
        const int p0 = tid * 4;                       // points p0..p0+3
        const float4* src = (const float4*)(rb + 3 * p0);   // 48B aligned? 48*tid -> 16B aligned ✓
        const float4 v0 = src[0], v1 = src[1], v2 = src[2];
        const float px[4] = {v0.x, v0.w, v1.z, v2.y};
        const float py[4] = {v0.y, v1.x, v1.w, v2.z};
        const float pz[4] = {v0.z, v1.y, v2.x, v2.w};
        #pragma unroll
        for (int k = 0; k < 4; ++k) {
            const int p = p0 + k;
            const float vx = px[k], vy = py[k], vz = pz[k];
            const unsigned short xh = f2b(vx), xl = f2b(vx - b2f(xh));
            const unsigned short yh = f2b(vy), yl = f2b(vy - b2f(yh));
            const unsigned short zh = f2b(vz), zl = f2b(vz - b2f(zh));
            const float nrm = fmaf(vx, vx, fmaf(vy, vy, vz * vz));
            const unsigned short nh = f2b(nrm), nl = f2b(nrm - b2f(nh));
            const unsigned base = ((unsigned)(p >> 5)) * 256u + ((unsigned)(p & 31)) * 4u;
            *(uint4*)(sB + base) =
                make_uint4(PK(xh, xl), PK(xh, xl), PK(yh, yl), PK(yh, yl));
            *(uint4*)(sB + base + 128) =
                make_uint4(PK(zh, zl), PK(zh, zl), PK(nh, nl), PK(ONEB, ONEB));
        }
    }

    // ---- build 2 query B-frags (stripe s: queries qs2*64 + s*32 + ln31) ----
    bf16x8 bq[2];
    #pragma unroll
    for (int s = 0; s < 2; ++s) {
        const float* qp = qb + (size_t)(s * 32 + ln31) * 3;
        const float vx = qp[0], vy = qp[1], vz = qp[2];
        const unsigned short xh = f2b(vx), xl = f2b(vx - b2f(xh));
        const unsigned short yh = f2b(vy), yl = f2b(vy - b2f(yh));
        const unsigned short zh = f2b(vz), zl = f2b(vz - b2f(zh));
        const float nrm = fmaf(vx, vx, fmaf(vy, vy, vz * vz));
        const unsigned short nh = f2b(nrm), nl = f2b(nrm - b2f(nh));
        const unsigned short mxh = f2b(-2.0f * b2f(xh)), mxl = f2b(-2.0f * b2f(xl));
        const unsigned short myh = f2b(-2.0f * b2f(yh)), myl = f2b(-2.0f * b2f(yl));
        const unsigned short mzh = f2b(-2.0f * b2f(zh)), mzl = f2b(-2.0f * b2f(zl));
        unsigned u[4];
        if (h == 0) {
            u[0] = PK(mxh, mxh); u[1] = PK(mxl, mxl);
            u[2] = PK(myh, myh); u[3] = PK(myl, myl);
        } else {
            u[0] = PK(mzh, mzh); u[1] = PK(mzl, mzl);
            u[2] = PK(ONEB, ONEB); u[3] = PK(nh, nl);
        }
        bq[s] = *(bf16x8*)u;
    }
    __syncthreads();

    // ---- main loop: 32 ref tiles, fully unrolled (immediate offsets) ----
    const f32x16 zacc = {};
    float mac00 = 3.4e38f, mac01 = 3.4e38f;   // stripe 0, parity 0/1
    float mac10 = 3.4e38f, mac11 = 3.4e38f;   // stripe 1, parity 0/1
    const unsigned* sBh = sB + half * 32 * 256 +
                          (unsigned)h * 128u + (unsigned)ln31 * 4u;

    #pragma unroll 32
    for (int t = 0; t < 32; ++t) {
        const bf16x8 af = *(const bf16x8*)(sBh + t * 256);
        const f32x16 d0 = __builtin_amdgcn_mfma_f32_32x32x16_bf16(af, bq[0], zacc, 0, 0, 0);
        const f32x16 d1 = __builtin_amdgcn_mfma_f32_32x32x16_bf16(af, bq[1], zacc, 0, 0, 0);
        if (t & 1) { mac01 = fminf(mac01, min16(d0)); mac11 = fminf(mac11, min16(d1)); }
        else       { mac00 = fminf(mac00, min16(d0)); mac10 = fminf(mac10, min16(d1)); }
    }

    // ---- epilogue: parities, k-halves, cross-tile-half combine, sum ----
    float m0 = fminf(mac00, mac01);
    float m1 = fminf(mac10, mac11);
    m0 = fminf(m0, __shfl_xor(m0, 32));           // other 16 ref rows
    m1 = fminf(m1, __shfl_xor(m1, 32));
    if (lane < 32) {
        pm[half][qs2][ln31]      = m0;
        pm[half][qs2][32 + ln31] = m1;
    }
    __syncthreads();

    if (tid < 256) {                               // 4 waves, 1 query each
        const float v = fminf(pm[0][tid >> 6][tid & 63],
                              pm[1][tid >> 6][tid & 63]);
        float s = v;
        s += __shfl_xor(s, 1);
        s += __shfl_xor(s, 2);
        s += __shfl_xor(s, 4);
        s += __shfl_xor(s, 8);
        s += __shfl_xor(s, 16);
        s += __shfl_xor(s, 32);
        if (lane == 0) sred[tid >> 6] = s;
    }
    __syncthreads();

    // ---- one pre-scaled atomic per block; out was memset to 0 ----
    if (tid == 0) {
        const float bs = (sred[0] + sred[1]) + (sred[2] + sred[3]);
        atomicAdd(out, bs * (1.0f / (float)PTS));
    }
}

extern "C" void kernel_launch(void* const* d_in, const int* in_sizes, int n_in,
                              void* d_out, int out_size, void* d_ws, size_t ws_size,
                              hipStream_t stream)
{
    const float* x = (const float*)d_in[0];
    const float* y = (const float*)d_in[1];
    float* out     = (float*)d_out;

    hipMemsetAsync(out, 0, sizeof(float), stream);
    chamfer_mfma_kernel<<<512, 512, 0, stream>>>(x, y, out);
}

// Round 18
// 17.646 us; speedup vs baseline: 1.3044x; 1.3044x over previous
//
#include <hip/hip_runtime.h>

// Chamfer distance via MFMA: x,y (32,2048,3) f32 -> scalar f32.
// d(q,r) = |r|^2 - 2 q.r + |q|^2 as a K=16 bf16 dot (hi/lo split, ~1e-4 err):
//   ref  row A[16] = [xh,xl,xh,xl, yh,yl,yh,yl, zh,zl,zh,zl, nh,nl, 1, 1 ]
//   query col B[16] = [-2qxh,-2qxh,-2qxl,-2qxl, ..y,z.., 1,1, qnh,qnl]
// One v_mfma_f32_32x32x16_bf16 -> 32 refs x 32 queries; refs as A rows makes
// the per-query min within-lane.
//
// Round-18: R12 two-kernel structure (plain stores -- atomic fusion falsified
// twice: R15 +6us, R17 +6us tails) with ONLY the two unconfounded R17 ideas:
//   * staging: 4 consecutive points/thread via 3 x global_load_dwordx4
//   * main loop fully unrolled (immediate ds_read offsets)
// Everything else bit-identical to R12 (tied-fastest, absmax 0).
// LDS panel: conflict-free [tile][k-half][slot32] (round 10).

#define B_  32
#define N_  2048
#define PTS (B_ * N_)
#define ONEB 0x3F80u

typedef short  bf16x8 __attribute__((ext_vector_type(8)));
typedef float  f32x16 __attribute__((ext_vector_type(16)));

__device__ __forceinline__ unsigned short f2b(float f) {
    unsigned u = __float_as_uint(f);
    return (unsigned short)((u + 0x7FFFu + ((u >> 16) & 1u)) >> 16);  // RNE
}
__device__ __forceinline__ float b2f(unsigned short h) {
    return __uint_as_float(((unsigned)h) << 16);
}
#define PK(a, b) (((unsigned)(a)) | (((unsigned)(b)) << 16))

// 16 -> 1 min, min3-shaped (fuses to v_min3_f32): 8 ops.
__device__ __forceinline__ float min16(const f32x16 d) {
    const float a = fminf(fminf(d[0],  d[1]),  d[2]);
    const float b = fminf(fminf(d[3],  d[4]),  d[5]);
    const float c = fminf(fminf(d[6],  d[7]),  d[8]);
    const float e = fminf(fminf(d[9],  d[10]), d[11]);
    const float f = fminf(fminf(d[12], d[13]), d[14]);
    const float g = fminf(fminf(a, b), c);
    const float i = fminf(fminf(e, f), d[15]);
    return fminf(g, i);
}

__global__ __launch_bounds__(512, 4) void chamfer_mfma_kernel(
    const float* __restrict__ x, const float* __restrict__ y,
    float* __restrict__ partial)
{
    __shared__ unsigned sB[N_ * 8];   // 64 KB, [tile][half][slot32] layout
    __shared__ float pm[2][4][64];    // 2 KB: [tile-half][stripe-pair][query]
    __shared__ float sred[4];

    const int bid  = blockIdx.x;      // 512
    const int dir  = bid >> 8;
    const int b    = (bid >> 3) & 31;
    const int qg   = bid & 7;         // 8 groups of 256 queries
    const int tid  = threadIdx.x;
    const int lane = tid & 63;
    const int wv   = tid >> 6;        // 0..7
    const int qs2  = wv & 3;          // stripe pair (64 queries)
    const int half = wv >> 2;         // which 32 ref tiles
    const int h    = lane >> 5;       // k-half
    const int ln31 = lane & 31;

    const float* q = dir ? y : x;
    const float* r = dir ? x : y;
    const float* rb = r + (size_t)b * N_ * 3;
    const float* qb = q + ((size_t)b * N_ + qg * 256 + qs2 * 64) * 3;

    // ---- stage ref panel: 4 consecutive points/thread, float4 loads ----
    {
        const int p0 = tid * 4;
        const float4* src = (const float4*)(rb + 3 * p0);  // 48B/thread, 16B-aligned
        const float4 v0 = src[0], v1 = src[1], v2 = src[2];
        const float px[4] = {v0.x, v0.w, v1.z, v2.y};
        const float py[4] = {v0.y, v1.x, v1.w, v2.z};
        const float pz[4] = {v0.z, v1.y, v2.x, v2.w};
        #pragma unroll
        for (int k = 0; k < 4; ++k) {
            const int p = p0 + k;
            const float vx = px[k], vy = py[k], vz = pz[k];
            const unsigned short xh = f2b(vx), xl = f2b(vx - b2f(xh));
            const unsigned short yh = f2b(vy), yl = f2b(vy - b2f(yh));
            const unsigned short zh = f2b(vz), zl = f2b(vz - b2f(zh));
            const float nrm = fmaf(vx, vx, fmaf(vy, vy, vz * vz));
            const unsigned short nh = f2b(nrm), nl = f2b(nrm - b2f(nh));
            const unsigned base = ((unsigned)(p >> 5)) * 256u + ((unsigned)(p & 31)) * 4u;
            *(uint4*)(sB + base) =
                make_uint4(PK(xh, xl), PK(xh, xl), PK(yh, yl), PK(yh, yl));
            *(uint4*)(sB + base + 128) =
                make_uint4(PK(zh, zl), PK(zh, zl), PK(nh, nl), PK(ONEB, ONEB));
        }
    }

    // ---- build 2 query B-frags (stripe s: queries qs2*64 + s*32 + ln31) ----
    bf16x8 bq[2];
    #pragma unroll
    for (int s = 0; s < 2; ++s) {
        const float* qp = qb + (size_t)(s * 32 + ln31) * 3;
        const float vx = qp[0], vy = qp[1], vz = qp[2];
        const unsigned short xh = f2b(vx), xl = f2b(vx - b2f(xh));
        const unsigned short yh = f2b(vy), yl = f2b(vy - b2f(yh));
        const unsigned short zh = f2b(vz), zl = f2b(vz - b2f(zh));
        const float nrm = fmaf(vx, vx, fmaf(vy, vy, vz * vz));
        const unsigned short nh = f2b(nrm), nl = f2b(nrm - b2f(nh));
        const unsigned short mxh = f2b(-2.0f * b2f(xh)), mxl = f2b(-2.0f * b2f(xl));
        const unsigned short myh = f2b(-2.0f * b2f(yh)), myl = f2b(-2.0f * b2f(yl));
        const unsigned short mzh = f2b(-2.0f * b2f(zh)), mzl = f2b(-2.0f * b2f(zl));
        unsigned u[4];
        if (h == 0) {
            u[0] = PK(mxh, mxh); u[1] = PK(mxl, mxl);
            u[2] = PK(myh, myh); u[3] = PK(myl, myl);
        } else {
            u[0] = PK(mzh, mzh); u[1] = PK(mzl, mzl);
            u[2] = PK(ONEB, ONEB); u[3] = PK(nh, nl);
        }
        bq[s] = *(bf16x8*)u;
    }
    __syncthreads();

    // ---- main loop: 32 ref tiles, fully unrolled, 1 ds_read -> 2 MFMAs ----
    const f32x16 zacc = {};
    float mac00 = 3.4e38f, mac01 = 3.4e38f;   // stripe 0, parity 0/1
    float mac10 = 3.4e38f, mac11 = 3.4e38f;   // stripe 1, parity 0/1
    const unsigned* sBh = sB + half * 32 * 256 +
                          (unsigned)h * 128u + (unsigned)ln31 * 4u;

    #pragma unroll 32
    for (int t = 0; t < 32; ++t) {
        const bf16x8 af = *(const bf16x8*)(sBh + t * 256);
        const f32x16 d0 = __builtin_amdgcn_mfma_f32_32x32x16_bf16(af, bq[0], zacc, 0, 0, 0);
        const f32x16 d1 = __builtin_amdgcn_mfma_f32_32x32x16_bf16(af, bq[1], zacc, 0, 0, 0);
        if (t & 1) { mac01 = fminf(mac01, min16(d0)); mac11 = fminf(mac11, min16(d1)); }
        else       { mac00 = fminf(mac00, min16(d0)); mac10 = fminf(mac10, min16(d1)); }
    }

    // ---- epilogue: parities, k-halves, cross-tile-half combine, sum ----
    float m0 = fminf(mac00, mac01);
    float m1 = fminf(mac10, mac11);
    m0 = fminf(m0, __shfl_xor(m0, 32));           // other 16 ref rows
    m1 = fminf(m1, __shfl_xor(m1, 32));
    if (lane < 32) {
        pm[half][qs2][ln31]      = m0;
        pm[half][qs2][32 + ln31] = m1;
    }
    __syncthreads();

    if (tid < 256) {                               // 4 waves, 1 query each
        const float v = fminf(pm[0][tid >> 6][tid & 63],
                              pm[1][tid >> 6][tid & 63]);
        float s = v;
        s += __shfl_xor(s, 1);
        s += __shfl_xor(s, 2);
        s += __shfl_xor(s, 4);
        s += __shfl_xor(s, 8);
        s += __shfl_xor(s, 16);
        s += __shfl_xor(s, 32);
        if (lane == 0) sred[tid >> 6] = s;
    }
    __syncthreads();
    if (tid == 0) partial[bid] = (sred[0] + sred[1]) + (sred[2] + sred[3]);
}

__global__ __launch_bounds__(256) void chamfer_final_kernel(
    const float* __restrict__ partial, float* __restrict__ out)
{
    const int tid = threadIdx.x;
    float s = partial[tid] + partial[tid + 256];
    #pragma unroll
    for (int off = 32; off > 0; off >>= 1) s += __shfl_down(s, off);
    __shared__ float sr[4];
    if ((tid & 63) == 0) sr[tid >> 6] = s;
    __syncthreads();
    if (tid == 0)
        out[0] = ((sr[0] + sr[1]) + (sr[2] + sr[3])) * (1.0f / (float)PTS);
}

extern "C" void kernel_launch(void* const* d_in, const int* in_sizes, int n_in,
                              void* d_out, int out_size, void* d_ws, size_t ws_size,
                              hipStream_t stream)
{
    const float* x = (const float*)d_in[0];
    const float* y = (const float*)d_in[1];
    float* partial = (float*)d_ws;            // 512 floats
    float* out     = (float*)d_out;

    chamfer_mfma_kernel<<<512, 512, 0, stream>>>(x, y, partial);
    chamfer_final_kernel<<<1, 256, 0, stream>>>(partial, out);
}

// Round 19
// 16.817 us; speedup vs baseline: 1.3687x; 1.0493x over previous
//
#include <hip/hip_runtime.h>

// Chamfer distance via MFMA, LDS-staged ref panel: x,y (32,2048,3) f32 -> scalar.
// d(q,r) = |r|^2 - 2 q.r + |q|^2 as a K=16 bf16 dot (hi/lo split, ~1e-4 err):
//   ref  row A[16] = [xh,xl,xh,xl, yh,yl,yh,yl, zh,zl,zh,zl, nh,nl, 1, 1 ]
//   query col B[16] = [-2qxh,-2qxh,-2qxl,-2qxl, ..y,z.., 1,1, qnh,qnl]
// One v_mfma_f32_32x32x16_bf16 -> 32 refs x 32 queries; refs as A rows makes
// the per-query min within-lane.
//
// FINAL (round-19): exact restore of round-11, the best-measured variant
// (16.84 us). Session falsification matrix: bank conflicts (R10), LDS read
// count (R12), min-VALU count (R12), occupancy 2/4/8 waves/SIMD (R11/R13),
// dependency shape (R16), kernel fusion (R15/R17: atomics cost +6us),
// staging vectorization + full unroll (R18) -- all neutral or negative
// against this structure. Residual ~9us over pipe floors is fixed
// per-dispatch/graph overhead, unreachable from kernel source.
//
//   512 blocks x 512 threads (8 waves, ONE 32-query stripe each) ->
//   2 blocks/CU = 4 waves/SIMD.  Running min is elementwise f32x16
//   (depth-1 dep on MFMA result; tree-reduce once in epilogue).
//   Per-iter wave body: 1 ds_read_b128 + 1 MFMA + 16 v_min.
// LDS: conflict-free [tile][k-half][slot32] layout (round 10).
// K2: sum 512 partials, scale by 1/(B*N).

#define B_  32
#define N_  2048
#define PTS (B_ * N_)
#define ONEB 0x3F80u

typedef short  bf16x8 __attribute__((ext_vector_type(8)));
typedef float  f32x16 __attribute__((ext_vector_type(16)));

__device__ __forceinline__ unsigned short f2b(float f) {
    unsigned u = __float_as_uint(f);
    return (unsigned short)((u + 0x7FFFu + ((u >> 16) & 1u)) >> 16);  // RNE
}
__device__ __forceinline__ float b2f(unsigned short h) {
    return __uint_as_float(((unsigned)h) << 16);
}
#define PK(a, b) (((unsigned)(a)) | (((unsigned)(b)) << 16))

__global__ __launch_bounds__(512, 4) void chamfer_mfma_kernel(
    const float* __restrict__ x, const float* __restrict__ y,
    float* __restrict__ partial)
{
    __shared__ unsigned sB[N_ * 8];   // 64 KB, [tile][half][slot32] layout

    const int bid  = blockIdx.x;      // 512
    const int dir  = bid >> 8;
    const int b    = (bid >> 3) & 31;
    const int qg   = bid & 7;         // 8 groups of 256 queries
    const int tid  = threadIdx.x;
    const int lane = tid & 63;
    const int wv   = tid >> 6;        // 0..7
    const int h    = lane >> 5;       // k-half
    const int ln31 = lane & 31;

    const float* q = dir ? y : x;
    const float* r = dir ? x : y;
    const float* rb = r + (size_t)b * N_ * 3;
    const float* qb = q + ((size_t)b * N_ + qg * 256 + wv * 32) * 3;

    // ---- stage ref panel into LDS (4 points per thread) ----
    for (int p = tid; p < N_; p += 512) {
        const float vx = rb[3 * p + 0], vy = rb[3 * p + 1], vz = rb[3 * p + 2];
        const unsigned short xh = f2b(vx), xl = f2b(vx - b2f(xh));
        const unsigned short yh = f2b(vy), yl = f2b(vy - b2f(yh));
        const unsigned short zh = f2b(vz), zl = f2b(vz - b2f(zh));
        const float nrm = fmaf(vx, vx, fmaf(vy, vy, vz * vz));
        const unsigned short nh = f2b(nrm), nl = f2b(nrm - b2f(nh));
        const unsigned base = ((unsigned)(p >> 5)) * 256u + ((unsigned)(p & 31)) * 4u;
        const uint4 lo = make_uint4(PK(xh, xl), PK(xh, xl), PK(yh, yl), PK(yh, yl));
        const uint4 hi = make_uint4(PK(zh, zl), PK(zh, zl), PK(nh, nl), PK(ONEB, ONEB));
        *(uint4*)(sB + base)        = lo;   // k-half 0
        *(uint4*)(sB + base + 128)  = hi;   // k-half 1
    }

    // ---- build this wave's query B-frag (32 queries) ----
    bf16x8 bq;
    {
        const float* qp = qb + (size_t)ln31 * 3;
        const float vx = qp[0], vy = qp[1], vz = qp[2];
        const unsigned short xh = f2b(vx), xl = f2b(vx - b2f(xh));
        const unsigned short yh = f2b(vy), yl = f2b(vy - b2f(yh));
        const unsigned short zh = f2b(vz), zl = f2b(vz - b2f(zh));
        const float nrm = fmaf(vx, vx, fmaf(vy, vy, vz * vz));
        const unsigned short nh = f2b(nrm), nl = f2b(nrm - b2f(nh));
        const unsigned short mxh = f2b(-2.0f * b2f(xh)), mxl = f2b(-2.0f * b2f(xl));
        const unsigned short myh = f2b(-2.0f * b2f(yh)), myl = f2b(-2.0f * b2f(yl));
        const unsigned short mzh = f2b(-2.0f * b2f(zh)), mzl = f2b(-2.0f * b2f(zl));
        unsigned u[4];
        if (h == 0) {
            u[0] = PK(mxh, mxh); u[1] = PK(mxl, mxl);
            u[2] = PK(myh, myh); u[3] = PK(myl, myl);
        } else {
            u[0] = PK(mzh, mzh); u[1] = PK(mzl, mzl);
            u[2] = PK(ONEB, ONEB); u[3] = PK(nh, nl);
        }
        bq = *(bf16x8*)u;
    }
    __syncthreads();

    // ---- main loop: 64 ref tiles, elementwise running min ----
    const f32x16 zacc = {};
    f32x16 maccv = zacc + 3.4e38f;
    const unsigned roff = (unsigned)h * 128u + (unsigned)ln31 * 4u;

    #pragma unroll 4
    for (int t = 0; t < 64; ++t) {
        const bf16x8 af = *(const bf16x8*)(sB + t * 256 + roff);
        const f32x16 d = __builtin_amdgcn_mfma_f32_32x32x16_bf16(af, bq, zacc, 0, 0, 0);
        maccv = __builtin_elementwise_min(maccv, d);
    }

    // ---- epilogue: tree-reduce 16 regs, combine k-halves, sum 32 queries ----
    float m0 = fminf(fminf(maccv[0],  maccv[1]),  fminf(maccv[2],  maccv[3]));
    float m1 = fminf(fminf(maccv[4],  maccv[5]),  fminf(maccv[6],  maccv[7]));
    float m2 = fminf(fminf(maccv[8],  maccv[9]),  fminf(maccv[10], maccv[11]));
    float m3 = fminf(fminf(maccv[12], maccv[13]), fminf(maccv[14], maccv[15]));
    float m  = fminf(fminf(m0, m1), fminf(m2, m3));
    m = fminf(m, __shfl_xor(m, 32));              // other 16 rows

    float s = m;                                   // lanes 0..31 distinct queries
    s += __shfl_xor(s, 1);
    s += __shfl_xor(s, 2);
    s += __shfl_xor(s, 4);
    s += __shfl_xor(s, 8);
    s += __shfl_xor(s, 16);                        // lane 0 (and 32): stripe sum

    __syncthreads();                               // sB done; reuse as sred
    float* sred = (float*)sB;
    if (lane == 0) sred[wv] = s;
    __syncthreads();
    if (tid == 0)
        partial[bid] = ((sred[0] + sred[1]) + (sred[2] + sred[3])) +
                       ((sred[4] + sred[5]) + (sred[6] + sred[7]));
}

__global__ __launch_bounds__(256) void chamfer_final_kernel(
    const float* __restrict__ partial, float* __restrict__ out)
{
    const int tid = threadIdx.x;
    float s = partial[tid] + partial[tid + 256];
    #pragma unroll
    for (int off = 32; off > 0; off >>= 1) s += __shfl_down(s, off);
    __shared__ float sr[4];
    if ((tid & 63) == 0) sr[tid >> 6] = s;
    __syncthreads();
    if (tid == 0)
        out[0] = ((sr[0] + sr[1]) + (sr[2] + sr[3])) * (1.0f / (float)PTS);
}

extern "C" void kernel_launch(void* const* d_in, const int* in_sizes, int n_in,
                              void* d_out, int out_size, void* d_ws, size_t ws_size,
                              hipStream_t stream)
{
    const float* x = (const float*)d_in[0];
    const float* y = (const float*)d_in[1];
    float* partial = (float*)d_ws;            // 512 floats
    float* out     = (float*)d_out;

    chamfer_mfma_kernel<<<512, 512, 0, stream>>>(x, y, partial);
    chamfer_final_kernel<<<1, 256, 0, stream>>>(partial, out);
}